// Round 18
// baseline (129.075 us; speedup 1.0000x reference)
//
#include <hip/hip_runtime.h>
#include <hip/hip_bf16.h>

// Problem constants
#define S_LEN   2048
#define BATCH   2
#define NH      16
#define DH      64
#define DMODEL  1024
#define MTOT    (BATCH * S_LEN)   // 4096

typedef __attribute__((ext_vector_type(4))) float f32x4;
typedef __attribute__((ext_vector_type(8))) short s16x8;   // 8 bf16
typedef __attribute__((ext_vector_type(4))) short s16x4;

#define MFMA_BF16(a, b, c) __builtin_amdgcn_mfma_f32_16x16x32_bf16((a), (b), (c), 0, 0, 0)

static __device__ __forceinline__ short f2bf(float f) {
    union { float f; unsigned u; } v; v.f = f;
    unsigned r = v.u + 0x7fffu + ((v.u >> 16) & 1u);
    return (short)(r >> 16);
}

static __device__ __forceinline__ unsigned cvtpk_bf16(float lo, float hi) {
    unsigned r;
    asm volatile("v_cvt_pk_bf16_f32 %0, %1, %2" : "=v"(r) : "v"(lo), "v"(hi));
    return r;
}

// async global->LDS, 16B per lane; dst is wave-uniform base (lane*16 added by HW)
static __device__ __forceinline__ void gload_lds16(const void* g, void* l) {
    __builtin_amdgcn_global_load_lds(
        (const __attribute__((address_space(1))) void*)g,
        (__attribute__((address_space(3))) void*)l, 16, 0, 0);
}

#define VM_WAIT(N) asm volatile("s_waitcnt vmcnt(" #N ")" ::: "memory")

// De-pinned barrier (m141 lesson): memory-only compile-time fences around a
// bare s_barrier.
static __device__ __forceinline__ void barrier_sync() {
    asm volatile("" ::: "memory");
    __builtin_amdgcn_s_barrier();
    asm volatile("" ::: "memory");
}

// ---------------------------------------------------------------------------
// Fused prep. grid (16,16,8):
//   z<4 : W[k][n] fp32 -> Wt[n][k] bf16 (transposed), z selects wq/wk/wv/wo
//   z>=4: x fp32 -> bf16, slice (z-4) of 4; z==4 also emits RoPE tables.
// ---------------------------------------------------------------------------
__global__ __launch_bounds__(256) void prep_all(const float* __restrict__ wq,
                                                const float* __restrict__ wk,
                                                const float* __restrict__ wv,
                                                const float* __restrict__ wo,
                                                const float* __restrict__ x,
                                                short* __restrict__ wtb,
                                                short* __restrict__ xb,
                                                float* __restrict__ cosT,
                                                float* __restrict__ sinT) {
    const int t = threadIdx.x;
    if (blockIdx.z < 4) {
        const float* W = (blockIdx.z == 0) ? wq : (blockIdx.z == 1) ? wk
                       : (blockIdx.z == 2) ? wv : wo;
        short* out = wtb + (size_t)blockIdx.z * DMODEL * DMODEL;

        __shared__ short T[64][72];
        const int k0 = blockIdx.y * 64, n0 = blockIdx.x * 64;

        #pragma unroll
        for (int p = 0; p < 4; ++p) {
            const int kk = p * 16 + (t >> 4);
            const int nn = (t & 15) * 4;
            f32x4 v = *(const f32x4*)(W + (size_t)(k0 + kk) * DMODEL + n0 + nn);
            #pragma unroll
            for (int j = 0; j < 4; ++j) T[nn + j][kk] = f2bf(v[j]);
        }
        __syncthreads();
        #pragma unroll
        for (int p = 0; p < 4; ++p) {
            const int nn = p * 16 + (t >> 4);
            const int kk = (t & 15) * 4;
            *(s16x4*)(out + (size_t)(n0 + nn) * DMODEL + k0 + kk) = *(const s16x4*)&T[nn][kk];
        }
    } else {
        const int slice = blockIdx.z - 4;               // 0..3
        const int blk = blockIdx.y * 16 + blockIdx.x;   // 0..255
        const size_t tb = ((size_t)(slice * 256 + blk) * 256 + t) * 16;
        #pragma unroll
        for (int jj = 0; jj < 2; ++jj) {
            const size_t i = tb + jj * 8;
            f32x4 a = *(const f32x4*)(x + i);
            f32x4 b = *(const f32x4*)(x + i + 4);
            s16x8 o;
            #pragma unroll
            for (int j = 0; j < 4; ++j) { o[j] = f2bf(a[j]); o[4 + j] = f2bf(b[j]); }
            *(s16x8*)(xb + i) = o;
        }
        if (slice == 0) {
            const int idx = blk * 256 + t;              // 65536 total
            const int s = idx >> 5, ii = idx & 31;
            const float inv = exp2f(-(float)ii * (13.287712379549449f / 32.0f));
            const float ang = (float)s * inv;
            cosT[idx] = cosf(ang);
            sinT[idx] = sinf(ang);
        }
    }
}

// ---------------------------------------------------------------------------
// 128x128 GEMM mainloop, BK=32, triple-buffered global_load_lds staging,
// issue-ahead-2, counted vmcnt(4). SM = 24576 shorts (48KB). (R11/R13 best.)
// ---------------------------------------------------------------------------
__device__ __forceinline__ void gemm_tile(const short* __restrict__ A,
                                          const short* __restrict__ Bt,
                                          int m0, int n0, short* SM,
                                          f32x4 acc[4][4]) {
    const int tid  = threadIdx.x;
    const int lane = tid & 63;
    const int wv   = tid >> 6;
    const int wm   = (wv >> 1) * 64;
    const int wn   = (wv & 1) * 64;
    const int g = lane >> 4, c16 = lane & 15;

    short* Asb = SM;
    short* Bsb = SM + 12288;

    const int srow = tid >> 2;                          // 0..63
    const int schk = (tid & 3) ^ ((tid >> 3) & 3);      // chunk ^ (row>>1)&3
    const short* ga0 = A  + (size_t)(m0 + srow)      * DMODEL + schk * 8;
    const short* ga1 = A  + (size_t)(m0 + 64 + srow) * DMODEL + schk * 8;
    const short* gb0 = Bt + (size_t)(n0 + srow)      * DMODEL + schk * 8;
    const short* gb1 = Bt + (size_t)(n0 + 64 + srow) * DMODEL + schk * 8;
    const int lw = wv * 512;

    #define STAGE_G(buf, ko) do { \
        gload_lds16(ga0 + (ko), Asb + (buf) * 4096 + lw); \
        gload_lds16(ga1 + (ko), Asb + (buf) * 4096 + 2048 + lw); \
        gload_lds16(gb0 + (ko), Bsb + (buf) * 4096 + lw); \
        gload_lds16(gb1 + (ko), Bsb + (buf) * 4096 + 2048 + lw); \
    } while (0)

    STAGE_G(0, 0);
    STAGE_G(1, 32);

    const int rlo = (g ^ ((c16 >> 1) & 3)) << 3;
    for (int ks = 0; ks < 32; ++ks) {
        if (ks < 31) { VM_WAIT(4); } else { VM_WAIT(0); }
        barrier_sync();
        if (ks + 2 < 32) STAGE_G((ks + 2) % 3, (ks + 2) * 32);
        const int cur = ks % 3;
        s16x8 af[4], bfr[4];
        #pragma unroll
        for (int i = 0; i < 4; ++i)
            af[i] = *(const s16x8*)&Asb[cur * 4096 + (wm + i * 16 + c16) * 32 + rlo];
        #pragma unroll
        for (int j = 0; j < 4; ++j)
            bfr[j] = *(const s16x8*)&Bsb[cur * 4096 + (wn + j * 16 + c16) * 32 + rlo];
        #pragma unroll
        for (int i = 0; i < 4; ++i)
            #pragma unroll
            for (int j = 0; j < 4; ++j)
                acc[i][j] = MFMA_BF16(af[i], bfr[j], acc[i][j]);
    }
    #undef STAGE_G
}

// ---------------------------------------------------------------------------
// 128x64 GEMM mainloop for the output projection: BK=32, triple-buffered,
// 3 loads/step, vmcnt(3) ahead-2.
// ---------------------------------------------------------------------------
__device__ __forceinline__ void gemm_tile64(const short* __restrict__ A,
                                            const short* __restrict__ Bt,
                                            int m0, int n0, short* SM,
                                            f32x4 acc[4][2]) {
    const int tid  = threadIdx.x;
    const int lane = tid & 63;
    const int wv   = tid >> 6;
    const int wm   = (wv >> 1) * 64;
    const int wn   = (wv & 1) * 32;
    const int g = lane >> 4, c16 = lane & 15;

    short* Asb = SM;
    short* Bsb = SM + 12288;                      // 3 bufs x 2048

    const int srow = tid >> 2;
    const int schk = (tid & 3) ^ ((tid >> 3) & 3);
    const short* ga0 = A  + (size_t)(m0 + srow)      * DMODEL + schk * 8;
    const short* ga1 = A  + (size_t)(m0 + 64 + srow) * DMODEL + schk * 8;
    const short* gb0 = Bt + (size_t)(n0 + srow)      * DMODEL + schk * 8;
    const int lw = wv * 512;

    #define SG64(buf, ko) do { \
        gload_lds16(ga0 + (ko), Asb + (buf) * 4096 + lw); \
        gload_lds16(ga1 + (ko), Asb + (buf) * 4096 + 2048 + lw); \
        gload_lds16(gb0 + (ko), Bsb + (buf) * 2048 + lw); \
    } while (0)

    SG64(0, 0);
    SG64(1, 32);

    const int rlo = (g ^ ((c16 >> 1) & 3)) << 3;
    for (int ks = 0; ks < 32; ++ks) {
        if (ks < 31) { VM_WAIT(3); } else { VM_WAIT(0); }
        barrier_sync();
        if (ks + 2 < 32) SG64((ks + 2) % 3, (ks + 2) * 32);
        const int cur = ks % 3;
        s16x8 af[4], bfr[2];
        #pragma unroll
        for (int i = 0; i < 4; ++i)
            af[i] = *(const s16x8*)&Asb[cur * 4096 + (wm + i * 16 + c16) * 32 + rlo];
        #pragma unroll
        for (int j = 0; j < 2; ++j)
            bfr[j] = *(const s16x8*)&Bsb[cur * 2048 + (wn + j * 16 + c16) * 32 + rlo];
        #pragma unroll
        for (int i = 0; i < 4; ++i)
            #pragma unroll
            for (int j = 0; j < 2; ++j)
                acc[i][j] = MFMA_BF16(af[i], bfr[j], acc[i][j]);
    }
    #undef SG64
}

// ---------------------------------------------------------------------------
// FUSED QKV GEMM (N=3072) + RoPE epilogue, coalesced LDS-repacked stores.
// grid (24,32) = 768 blocks = 3/CU. Balanced XCD remap. (R17 state.)
// ---------------------------------------------------------------------------
__global__ __launch_bounds__(256) void gemm_qkv(const short* __restrict__ xb,
                                                const short* __restrict__ wtb,
                                                short* __restrict__ Qo,
                                                short* __restrict__ Ko,
                                                short* __restrict__ Vt,
                                                const float* __restrict__ cosT,
                                                const float* __restrict__ sinT) {
    __shared__ __align__(16) short SM[24576];     // 48KB: staging, then repack

    const int dd    = blockIdx.x + 24 * blockIdx.y;  // xcd = dd%8
    const int xcd   = dd & 7;
    const int local = dd >> 3;                       // 0..95
    const int ty = (xcd & 3) * 8 + local / 12;       // 0..31
    const int tx = (xcd >> 2) * 12 + local % 12;     // 0..23
    const int m0 = ty * 128, n0 = tx * 128;
    const int z  = tx >> 3;                       // 0:Q 1:K 2:V (uniform/block)

    f32x4 acc[4][4] = {};
    gemm_tile(xb, wtb, m0, n0, SM, acc);

    const int tid  = threadIdx.x;
    const int lane = tid & 63;
    const int wv   = tid >> 6;
    const int wm   = (wv >> 1) * 64, wn = (wv & 1) * 64;
    const int g = lane >> 4, c16 = lane & 15;
    const int hbase = (n0 & 1023) >> 6;

    barrier_sync();                               // staging reads done -> reuse SM
    short (*RP)[136] = (short(*)[136])SM;         // 128 x 136 shorts

    if (z < 2) {
        short* outp = (z == 0) ? Qo : Ko;
        const float post = (z == 0) ? 0.18033688011112042f : 1.0f;  // 0.125*log2(e)
        #pragma unroll
        for (int j = 0; j < 4; ++j) {
            const int nl = wn + j * 16 + c16;
            const int d  = (n0 + nl) & 63;
            #pragma unroll
            for (int i = 0; i < 4; ++i) {
                #pragma unroll
                for (int r = 0; r < 4; ++r) {
                    const int ml = wm + i * 16 + g * 4 + r;
                    const int s  = (m0 + ml) & (S_LEN - 1);
                    float v = acc[i][j][r];
                    float vo = __shfl_xor(v, 1, 64);   // partner col = n^1
                    float cs = cosT[s * 32 + (d >> 1)];
                    float sn = sinT[s * 32 + (d >> 1)];
                    float res = (d & 1) ? (vo * sn + v * cs) : (v * cs - vo * sn);
                    RP[ml][nl] = f2bf(res * post);
                }
            }
        }
        barrier_sync();
        #pragma unroll
        for (int pass = 0; pass < 8; ++pass) {
            const int row = pass * 32 + (tid >> 3);   // 0..255
            const int k   = tid & 7;
            const int hh = row >> 7, ss = row & 127;
            const int m = m0 + ss;
            const int s = m & (S_LEN - 1), b = m >> 11;
            short* dst = outp + (((size_t)b * NH + hbase + hh) * S_LEN + s) * DH + k * 8;
            *(s16x8*)dst = *(const s16x8*)&RP[ss][hh * 64 + k * 8];
        }
    } else {
        #pragma unroll
        for (int j = 0; j < 4; ++j) {
            const int nl = wn + j * 16 + c16;
            #pragma unroll
            for (int i = 0; i < 4; ++i) {
                const int mlb = wm + i * 16 + g * 4;
                s16x4 pk;
                #pragma unroll
                for (int r = 0; r < 4; ++r) pk[r] = f2bf(acc[i][j][r]);
                *(s16x4*)&RP[nl][mlb] = pk;
            }
        }
        barrier_sync();
        const int b = m0 >> 11, sr0 = m0 & (S_LEN - 1);
        #pragma unroll
        for (int pass = 0; pass < 8; ++pass) {
            const int row = pass * 16 + (tid >> 4);   // 0..127 (h,d rows)
            const int k   = tid & 15;
            const int h = hbase + (row >> 6), d = row & 63;
            short* dst = Vt + (((size_t)b * NH + h) * DH + d) * S_LEN + sr0 + k * 8;
            *(s16x8*)dst = *(const s16x8*)&RP[row][k * 8];
        }
    }
}

// ---------------------------------------------------------------------------
// Causal flash attention, DUAL-Q v2. Grid (32 bh-FAST, 16):
//   bh = blockIdx.x  -> xcd = bid%8 = bh%8: each XCD serves 4 heads
//   (2MB K/V L2-resident — the R15 locality property R16 broke).
//   ci = (by<8) ? 15-by : by-8 -> CU pair (bid, bid+256) sums to 36 tiles.
// Wave w owns 32 q rows [ci*128+32w, +32) as 2 q-groups; each K/V fragment
// read feeds BOTH q-groups (per-q LDS reads/staging/barriers halve).
// Last compute tile tw = 2ci+(w>>1); qrel = (w&1)*32 + qg*16 + c16.
// Double-buffered K/V; lane-local no-max softmax (Q pre-scaled).
// ---------------------------------------------------------------------------
__global__ __launch_bounds__(256) void attn(const short* __restrict__ Q,
                                            const short* __restrict__ K,
                                            const short* __restrict__ Vt,
                                            short* __restrict__ O) {
    const int tid  = threadIdx.x;
    const int lane = tid & 63;
    const int w    = tid >> 6;
    const int g = lane >> 4, c16 = lane & 15;

    const int bh = blockIdx.x;                    // 0..31 (fast axis: L2 map)
    const int a  = blockIdx.y;                    // 0..15
    const int ci = (a < 8) ? (15 - a) : (a - 8);  // paired-ci LPT balance
    const int ntiles = 2 * ci + 2;
    const int tw = 2 * ci + (w >> 1);             // wave's last compute tile
    const int wq0 = ci * 128 + w * 32;
    const size_t base = (size_t)bh * S_LEN * DH;
    const short* Kb = K + base;
    const short* Vb = Vt + (size_t)bh * DH * S_LEN;
    const int b = bh >> 4, h = bh & 15;

    __shared__ __align__(16) short KL[2][4096];     // [64 kv][64 d] swz chunks
    __shared__ __align__(16) short VL[2][4096];     // [64 d][64 kv] swz chunks
    __shared__ __align__(16) short P2[4][2][16][72];// per-wave, per-qg P^T

    const int kr = tid >> 3;                      // 0..31
    const int kc = (tid & 7) ^ (kr & 7);
    const short* kg0 = Kb + (size_t)kr * DH + (kc << 3);
    const short* kg1 = Kb + (size_t)(32 + kr) * DH + (kc << 3);
    const short* vg0 = Vb + (size_t)kr * S_LEN + (kc << 3);
    const short* vg1 = Vb + (size_t)(32 + kr) * S_LEN + (kc << 3);
    const int lw = w * 512;                       // wave-uniform LDS base
    const int kx = c16 & 7;

    // prologue: tile 0 -> buf0; Q fragments for both q-groups
    gload_lds16(kg0, &KL[0][lw]);
    gload_lds16(kg1, &KL[0][2048 + lw]);
    gload_lds16(vg0, &VL[0][lw]);
    gload_lds16(vg1, &VL[0][2048 + lw]);
    s16x8 bq[2][2];
    #pragma unroll
    for (int qg = 0; qg < 2; ++qg) {
        const short* qp = Q + base + (size_t)(wq0 + qg * 16 + c16) * DH;
        bq[qg][0] = *(const s16x8*)(qp + g * 8);
        bq[qg][1] = *(const s16x8*)(qp + 32 + g * 8);
    }
    VM_WAIT(0);
    barrier_sync();

    f32x4 o[2][4] = {};
    float lsum[2] = {};

    for (int tt = 0; tt < ntiles; ++tt) {
        const int cur = tt & 1;
        const bool more = (tt + 1 < ntiles);
        if (more) {
            const size_t ko = (size_t)(tt + 1) * 64;
            gload_lds16(kg0 + ko * DH, &KL[cur ^ 1][lw]);
            gload_lds16(kg1 + ko * DH, &KL[cur ^ 1][2048 + lw]);
            gload_lds16(vg0 + ko,      &VL[cur ^ 1][lw]);
            gload_lds16(vg1 + ko,      &VL[cur ^ 1][2048 + lw]);
        }

        if (tt <= tw) {
            // K frags once -> feed both q-groups
            s16x8 kf[4][2];
            #pragma unroll
            for (int cg = 0; cg < 4; ++cg) {
                const int krow = (cg * 16 + c16) * 64;
                kf[cg][0] = *(const s16x8*)&KL[cur][krow + ((g ^ kx) << 3)];
                kf[cg][1] = *(const s16x8*)&KL[cur][krow + (((4 + g) ^ kx) << 3)];
            }
            // QK^T swapped: s[qg][cg] = S^T[kv][q=c16]
            f32x4 s[2][4];
            __builtin_amdgcn_s_setprio(1);
            #pragma unroll
            for (int qg = 0; qg < 2; ++qg)
                #pragma unroll
                for (int cg = 0; cg < 4; ++cg) {
                    f32x4 zz = {};
                    zz = MFMA_BF16(kf[cg][0], bq[qg][0], zz);
                    s[qg][cg] = MFMA_BF16(kf[cg][1], bq[qg][1], zz);
                }
            __builtin_amdgcn_s_setprio(0);

            // V frags once -> feed both q-groups
            s16x8 vf[4][2];
            #pragma unroll
            for (int nt = 0; nt < 4; ++nt) {
                const int vr = (nt * 16 + c16) * 64;
                vf[nt][0] = *(const s16x8*)&VL[cur][vr + ((g ^ kx) << 3)];
                vf[nt][1] = *(const s16x8*)&VL[cur][vr + (((4 + g) ^ kx) << 3)];
            }

            const bool diag = (tt == tw);
            #pragma unroll
            for (int qg = 0; qg < 2; ++qg) {
                const int qrel = (w & 1) * 32 + qg * 16 + c16;
                #pragma unroll
                for (int cg = 0; cg < 4; ++cg) {
                    float e[4];
                    #pragma unroll
                    for (int r = 0; r < 4; ++r) {
                        e[r] = exp2f(s[qg][cg][r]);
                        if (diag && (cg * 16 + g * 4 + r > qrel)) e[r] = 0.f;
                    }
                    lsum[qg] += (e[0] + e[1]) + (e[2] + e[3]);
                    uint2 pk;
                    pk.x = cvtpk_bf16(e[0], e[1]);
                    pk.y = cvtpk_bf16(e[2], e[3]);
                    *(uint2*)&P2[w][qg][c16][cg * 16 + g * 4] = pk;
                }
            }
            asm volatile("s_waitcnt lgkmcnt(0)" ::: "memory");
            s16x8 ap[2][2];
            #pragma unroll
            for (int qg = 0; qg < 2; ++qg) {
                ap[qg][0] = *(const s16x8*)&P2[w][qg][c16][g * 8];
                ap[qg][1] = *(const s16x8*)&P2[w][qg][c16][32 + g * 8];
            }
            __builtin_amdgcn_s_setprio(1);
            #pragma unroll
            for (int qg = 0; qg < 2; ++qg)
                #pragma unroll
                for (int nt = 0; nt < 4; ++nt) {
                    o[qg][nt] = MFMA_BF16(ap[qg][0], vf[nt][0], o[qg][nt]);
                    o[qg][nt] = MFMA_BF16(ap[qg][1], vf[nt][1], o[qg][nt]);
                }
            __builtin_amdgcn_s_setprio(0);
        }

        if (more) { VM_WAIT(0); }                 // next tile landed
        barrier_sync();
    }

    // epilogue: per q-group, reduce l across the 4 kv lane-groups, write Ob
    #pragma unroll
    for (int qg = 0; qg < 2; ++qg) {
        float lt = lsum[qg];
        lt += __shfl_xor(lt, 16, 64);
        lt += __shfl_xor(lt, 32, 64);
        #pragma unroll
        for (int r = 0; r < 4; ++r) {
            const float linv = 1.0f / __shfl(lt, g * 4 + r, 64);
            #pragma unroll
            for (int nt = 0; nt < 4; ++nt) {
                O[((size_t)(b * S_LEN + wq0 + qg * 16 + g * 4 + r)) * DMODEL
                  + h * DH + nt * 16 + c16] = f2bf(o[qg][nt][r] * linv);
            }
        }
    }
}

// ---------------------------------------------------------------------------
// Output projection: C = Ob(bf16) @ wo, fp32 out. 128x64 tiles, grid (16,32)
// = 512 blocks = 2/CU. XCD remap. (R17 state.)
// ---------------------------------------------------------------------------
__global__ __launch_bounds__(256) void gemm_o(const short* __restrict__ Ob,
                                              const short* __restrict__ WoT,
                                              float* __restrict__ C) {
    __shared__ __align__(16) short SMl[18432];    // 36KB

    const int dd = blockIdx.x + 16 * blockIdx.y;  // 0..511, xcd = dd%8
    const int ti = (dd & 7) * 64 + (dd >> 3);     // bijective (512 = 8*64)
    const int tx = ti & 15, ty = ti >> 4;         // ty in [4*xcd, +4)
    const int m0 = ty * 128, n0 = tx * 64;

    f32x4 acc[4][2] = {};
    gemm_tile64(Ob, WoT, m0, n0, SMl, acc);

    const int tid  = threadIdx.x;
    const int lane = tid & 63;
    const int wv   = tid >> 6;
    const int wm   = (wv >> 1) * 64, wn = (wv & 1) * 32;
    const int g = lane >> 4, c16 = lane & 15;

    #pragma unroll
    for (int i = 0; i < 4; ++i)
        #pragma unroll
        for (int j = 0; j < 2; ++j) {
            const int n = n0 + wn + j * 16 + c16;
            #pragma unroll
            for (int r = 0; r < 4; ++r) {
                const int m = m0 + wm + i * 16 + g * 4 + r;
                C[(size_t)m * DMODEL + n] = acc[i][j][r];
            }
        }
}

// ---------------------------------------------------------------------------
extern "C" void kernel_launch(void* const* d_in, const int* in_sizes, int n_in,
                              void* d_out, int out_size, void* d_ws, size_t ws_size,
                              hipStream_t stream) {
    const float* x  = (const float*)d_in[0];
    const float* wq = (const float*)d_in[1];
    const float* wk = (const float*)d_in[2];
    const float* wv = (const float*)d_in[3];
    const float* wo = (const float*)d_in[4];
    float* out = (float*)d_out;

    char* ws = (char*)d_ws;
    short* wtb  = (short*)ws;                              // [4][1024][1024] bf16 (q,k,v,o)
    short* xb   = (short*)(ws + (8ull  << 20));            // [4096][1024] bf16
    float* cosT = (float*)(ws + (16ull << 20));            // [2048][32]
    float* sinT = (float*)(ws + (16ull << 20) + (256ull << 10));
    short* Qb   = (short*)(ws + (17ull << 20));            // [B*H][S][64] bf16 (pre-scaled)
    short* Kb   = (short*)(ws + (25ull << 20));            // [B*H][S][64] bf16
    short* Vtb  = (short*)(ws + (33ull << 20));            // [B*H][64][S] bf16 (transposed)
    short* Ob   = (short*)(ws + (41ull << 20));            // [4096][1024] bf16

    prep_all<<<dim3(16, 16, 8), 256, 0, stream>>>(wq, wk, wv, wo, x,
                                                  wtb, xb, cosT, sinT);

    gemm_qkv<<<dim3(24, 32), 256, 0, stream>>>(xb, wtb, Qb, Kb, Vtb, cosT, sinT);
    attn    <<<dim3(32, 16), 256, 0, stream>>>(Qb, Kb, Vtb, Ob);
    gemm_o  <<<dim3(16, 32), 256, 0, stream>>>(Ob, wtb + 3ull * DMODEL * DMODEL, out);
}

// Round 19
// 109.231 us; speedup vs baseline: 1.1817x; 1.1817x over previous
//
#include <hip/hip_runtime.h>
#include <hip/hip_bf16.h>

// Problem constants
#define S_LEN   2048
#define BATCH   2
#define NH      16
#define DH      64
#define DMODEL  1024
#define MTOT    (BATCH * S_LEN)   // 4096

typedef __attribute__((ext_vector_type(4))) float f32x4;
typedef __attribute__((ext_vector_type(8))) short s16x8;   // 8 bf16
typedef __attribute__((ext_vector_type(4))) short s16x4;

#define MFMA_BF16(a, b, c) __builtin_amdgcn_mfma_f32_16x16x32_bf16((a), (b), (c), 0, 0, 0)

static __device__ __forceinline__ short f2bf(float f) {
    union { float f; unsigned u; } v; v.f = f;
    unsigned r = v.u + 0x7fffu + ((v.u >> 16) & 1u);
    return (short)(r >> 16);
}

static __device__ __forceinline__ unsigned cvtpk_bf16(float lo, float hi) {
    unsigned r;
    asm volatile("v_cvt_pk_bf16_f32 %0, %1, %2" : "=v"(r) : "v"(lo), "v"(hi));
    return r;
}

// async global->LDS, 16B per lane; dst is wave-uniform base (lane*16 added by HW)
static __device__ __forceinline__ void gload_lds16(const void* g, void* l) {
    __builtin_amdgcn_global_load_lds(
        (const __attribute__((address_space(1))) void*)g,
        (__attribute__((address_space(3))) void*)l, 16, 0, 0);
}

#define VM_WAIT(N) asm volatile("s_waitcnt vmcnt(" #N ")" ::: "memory")

// De-pinned barrier (m141 lesson): memory-only compile-time fences around a
// bare s_barrier.
static __device__ __forceinline__ void barrier_sync() {
    asm volatile("" ::: "memory");
    __builtin_amdgcn_s_barrier();
    asm volatile("" ::: "memory");
}

// ---------------------------------------------------------------------------
// Fused prep. grid (16,16,8):
//   z<4 : W[k][n] fp32 -> Wt[n][k] bf16 (transposed), z selects wq/wk/wv/wo
//   z>=4: x fp32 -> bf16, slice (z-4) of 4; z==4 also emits RoPE tables.
// ---------------------------------------------------------------------------
__global__ __launch_bounds__(256) void prep_all(const float* __restrict__ wq,
                                                const float* __restrict__ wk,
                                                const float* __restrict__ wv,
                                                const float* __restrict__ wo,
                                                const float* __restrict__ x,
                                                short* __restrict__ wtb,
                                                short* __restrict__ xb,
                                                float* __restrict__ cosT,
                                                float* __restrict__ sinT) {
    const int t = threadIdx.x;
    if (blockIdx.z < 4) {
        const float* W = (blockIdx.z == 0) ? wq : (blockIdx.z == 1) ? wk
                       : (blockIdx.z == 2) ? wv : wo;
        short* out = wtb + (size_t)blockIdx.z * DMODEL * DMODEL;

        __shared__ short T[64][72];
        const int k0 = blockIdx.y * 64, n0 = blockIdx.x * 64;

        #pragma unroll
        for (int p = 0; p < 4; ++p) {
            const int kk = p * 16 + (t >> 4);
            const int nn = (t & 15) * 4;
            f32x4 v = *(const f32x4*)(W + (size_t)(k0 + kk) * DMODEL + n0 + nn);
            #pragma unroll
            for (int j = 0; j < 4; ++j) T[nn + j][kk] = f2bf(v[j]);
        }
        __syncthreads();
        #pragma unroll
        for (int p = 0; p < 4; ++p) {
            const int nn = p * 16 + (t >> 4);
            const int kk = (t & 15) * 4;
            *(s16x4*)(out + (size_t)(n0 + nn) * DMODEL + k0 + kk) = *(const s16x4*)&T[nn][kk];
        }
    } else {
        const int slice = blockIdx.z - 4;               // 0..3
        const int blk = blockIdx.y * 16 + blockIdx.x;   // 0..255
        const size_t tb = ((size_t)(slice * 256 + blk) * 256 + t) * 16;
        #pragma unroll
        for (int jj = 0; jj < 2; ++jj) {
            const size_t i = tb + jj * 8;
            f32x4 a = *(const f32x4*)(x + i);
            f32x4 b = *(const f32x4*)(x + i + 4);
            s16x8 o;
            #pragma unroll
            for (int j = 0; j < 4; ++j) { o[j] = f2bf(a[j]); o[4 + j] = f2bf(b[j]); }
            *(s16x8*)(xb + i) = o;
        }
        if (slice == 0) {
            const int idx = blk * 256 + t;              // 65536 total
            const int s = idx >> 5, ii = idx & 31;
            const float inv = exp2f(-(float)ii * (13.287712379549449f / 32.0f));
            const float ang = (float)s * inv;
            cosT[idx] = cosf(ang);
            sinT[idx] = sinf(ang);
        }
    }
}

// ---------------------------------------------------------------------------
// 128x128 GEMM mainloop, BK=32, triple-buffered global_load_lds staging,
// issue-ahead-2, counted vmcnt(4). SM = 24576 shorts (48KB). (R11/R13 best.)
// ---------------------------------------------------------------------------
__device__ __forceinline__ void gemm_tile(const short* __restrict__ A,
                                          const short* __restrict__ Bt,
                                          int m0, int n0, short* SM,
                                          f32x4 acc[4][4]) {
    const int tid  = threadIdx.x;
    const int lane = tid & 63;
    const int wv   = tid >> 6;
    const int wm   = (wv >> 1) * 64;
    const int wn   = (wv & 1) * 64;
    const int g = lane >> 4, c16 = lane & 15;

    short* Asb = SM;
    short* Bsb = SM + 12288;

    const int srow = tid >> 2;                          // 0..63
    const int schk = (tid & 3) ^ ((tid >> 3) & 3);      // chunk ^ (row>>1)&3
    const short* ga0 = A  + (size_t)(m0 + srow)      * DMODEL + schk * 8;
    const short* ga1 = A  + (size_t)(m0 + 64 + srow) * DMODEL + schk * 8;
    const short* gb0 = Bt + (size_t)(n0 + srow)      * DMODEL + schk * 8;
    const short* gb1 = Bt + (size_t)(n0 + 64 + srow) * DMODEL + schk * 8;
    const int lw = wv * 512;

    #define STAGE_G(buf, ko) do { \
        gload_lds16(ga0 + (ko), Asb + (buf) * 4096 + lw); \
        gload_lds16(ga1 + (ko), Asb + (buf) * 4096 + 2048 + lw); \
        gload_lds16(gb0 + (ko), Bsb + (buf) * 4096 + lw); \
        gload_lds16(gb1 + (ko), Bsb + (buf) * 4096 + 2048 + lw); \
    } while (0)

    STAGE_G(0, 0);
    STAGE_G(1, 32);

    const int rlo = (g ^ ((c16 >> 1) & 3)) << 3;
    for (int ks = 0; ks < 32; ++ks) {
        if (ks < 31) { VM_WAIT(4); } else { VM_WAIT(0); }
        barrier_sync();
        if (ks + 2 < 32) STAGE_G((ks + 2) % 3, (ks + 2) * 32);
        const int cur = ks % 3;
        s16x8 af[4], bfr[4];
        #pragma unroll
        for (int i = 0; i < 4; ++i)
            af[i] = *(const s16x8*)&Asb[cur * 4096 + (wm + i * 16 + c16) * 32 + rlo];
        #pragma unroll
        for (int j = 0; j < 4; ++j)
            bfr[j] = *(const s16x8*)&Bsb[cur * 4096 + (wn + j * 16 + c16) * 32 + rlo];
        #pragma unroll
        for (int i = 0; i < 4; ++i)
            #pragma unroll
            for (int j = 0; j < 4; ++j)
                acc[i][j] = MFMA_BF16(af[i], bfr[j], acc[i][j]);
    }
    #undef STAGE_G
}

// ---------------------------------------------------------------------------
// 128x64 GEMM mainloop for the output projection: BK=32, triple-buffered,
// 3 loads/step, vmcnt(3) ahead-2.
// ---------------------------------------------------------------------------
__device__ __forceinline__ void gemm_tile64(const short* __restrict__ A,
                                            const short* __restrict__ Bt,
                                            int m0, int n0, short* SM,
                                            f32x4 acc[4][2]) {
    const int tid  = threadIdx.x;
    const int lane = tid & 63;
    const int wv   = tid >> 6;
    const int wm   = (wv >> 1) * 64;
    const int wn   = (wv & 1) * 32;
    const int g = lane >> 4, c16 = lane & 15;

    short* Asb = SM;
    short* Bsb = SM + 12288;                      // 3 bufs x 2048

    const int srow = tid >> 2;
    const int schk = (tid & 3) ^ ((tid >> 3) & 3);
    const short* ga0 = A  + (size_t)(m0 + srow)      * DMODEL + schk * 8;
    const short* ga1 = A  + (size_t)(m0 + 64 + srow) * DMODEL + schk * 8;
    const short* gb0 = Bt + (size_t)(n0 + srow)      * DMODEL + schk * 8;
    const int lw = wv * 512;

    #define SG64(buf, ko) do { \
        gload_lds16(ga0 + (ko), Asb + (buf) * 4096 + lw); \
        gload_lds16(ga1 + (ko), Asb + (buf) * 4096 + 2048 + lw); \
        gload_lds16(gb0 + (ko), Bsb + (buf) * 2048 + lw); \
    } while (0)

    SG64(0, 0);
    SG64(1, 32);

    const int rlo = (g ^ ((c16 >> 1) & 3)) << 3;
    for (int ks = 0; ks < 32; ++ks) {
        if (ks < 31) { VM_WAIT(3); } else { VM_WAIT(0); }
        barrier_sync();
        if (ks + 2 < 32) SG64((ks + 2) % 3, (ks + 2) * 32);
        const int cur = ks % 3;
        s16x8 af[4], bfr[2];
        #pragma unroll
        for (int i = 0; i < 4; ++i)
            af[i] = *(const s16x8*)&Asb[cur * 4096 + (wm + i * 16 + c16) * 32 + rlo];
        #pragma unroll
        for (int j = 0; j < 2; ++j)
            bfr[j] = *(const s16x8*)&Bsb[cur * 2048 + (wn + j * 16 + c16) * 32 + rlo];
        #pragma unroll
        for (int i = 0; i < 4; ++i)
            #pragma unroll
            for (int j = 0; j < 2; ++j)
                acc[i][j] = MFMA_BF16(af[i], bfr[j], acc[i][j]);
    }
    #undef SG64
}

// ---------------------------------------------------------------------------
// FUSED QKV GEMM (N=3072) + RoPE epilogue, coalesced LDS-repacked stores.
// grid (24,32) = 768 blocks = 3/CU. Balanced XCD remap (12tx x 8ty per XCD).
// ---------------------------------------------------------------------------
__global__ __launch_bounds__(256) void gemm_qkv(const short* __restrict__ xb,
                                                const short* __restrict__ wtb,
                                                short* __restrict__ Qo,
                                                short* __restrict__ Ko,
                                                short* __restrict__ Vt,
                                                const float* __restrict__ cosT,
                                                const float* __restrict__ sinT) {
    __shared__ __align__(16) short SM[24576];     // 48KB: staging, then repack

    const int dd    = blockIdx.x + 24 * blockIdx.y;  // xcd = dd%8
    const int xcd   = dd & 7;
    const int local = dd >> 3;                       // 0..95
    const int ty = (xcd & 3) * 8 + local / 12;       // 0..31
    const int tx = (xcd >> 2) * 12 + local % 12;     // 0..23
    const int m0 = ty * 128, n0 = tx * 128;
    const int z  = tx >> 3;                       // 0:Q 1:K 2:V (uniform/block)

    f32x4 acc[4][4] = {};
    gemm_tile(xb, wtb, m0, n0, SM, acc);

    const int tid  = threadIdx.x;
    const int lane = tid & 63;
    const int wv   = tid >> 6;
    const int wm   = (wv >> 1) * 64, wn = (wv & 1) * 64;
    const int g = lane >> 4, c16 = lane & 15;
    const int hbase = (n0 & 1023) >> 6;

    barrier_sync();                               // staging reads done -> reuse SM
    short (*RP)[136] = (short(*)[136])SM;         // 128 x 136 shorts

    if (z < 2) {
        short* outp = (z == 0) ? Qo : Ko;
        const float post = (z == 0) ? 0.18033688011112042f : 1.0f;  // 0.125*log2(e)
        #pragma unroll
        for (int j = 0; j < 4; ++j) {
            const int nl = wn + j * 16 + c16;
            const int d  = (n0 + nl) & 63;
            #pragma unroll
            for (int i = 0; i < 4; ++i) {
                #pragma unroll
                for (int r = 0; r < 4; ++r) {
                    const int ml = wm + i * 16 + g * 4 + r;
                    const int s  = (m0 + ml) & (S_LEN - 1);
                    float v = acc[i][j][r];
                    float vo = __shfl_xor(v, 1, 64);   // partner col = n^1
                    float cs = cosT[s * 32 + (d >> 1)];
                    float sn = sinT[s * 32 + (d >> 1)];
                    float res = (d & 1) ? (vo * sn + v * cs) : (v * cs - vo * sn);
                    RP[ml][nl] = f2bf(res * post);
                }
            }
        }
        barrier_sync();
        #pragma unroll
        for (int pass = 0; pass < 8; ++pass) {
            const int row = pass * 32 + (tid >> 3);   // 0..255
            const int k   = tid & 7;
            const int hh = row >> 7, ss = row & 127;
            const int m = m0 + ss;
            const int s = m & (S_LEN - 1), b = m >> 11;
            short* dst = outp + (((size_t)b * NH + hbase + hh) * S_LEN + s) * DH + k * 8;
            *(s16x8*)dst = *(const s16x8*)&RP[ss][hh * 64 + k * 8];
        }
    } else {
        #pragma unroll
        for (int j = 0; j < 4; ++j) {
            const int nl = wn + j * 16 + c16;
            #pragma unroll
            for (int i = 0; i < 4; ++i) {
                const int mlb = wm + i * 16 + g * 4;
                s16x4 pk;
                #pragma unroll
                for (int r = 0; r < 4; ++r) pk[r] = f2bf(acc[i][j][r]);
                *(s16x4*)&RP[nl][mlb] = pk;
            }
        }
        barrier_sync();
        const int b = m0 >> 11, sr0 = m0 & (S_LEN - 1);
        #pragma unroll
        for (int pass = 0; pass < 8; ++pass) {
            const int row = pass * 16 + (tid >> 4);   // 0..127 (h,d rows)
            const int k   = tid & 15;
            const int h = hbase + (row >> 6), d = row & 63;
            short* dst = Vt + (((size_t)b * NH + h) * DH + d) * S_LEN + sr0 + k * 8;
            *(s16x8*)dst = *(const s16x8*)&RP[row][k * 8];
        }
    }
}

// ---------------------------------------------------------------------------
// Causal flash attention. grid (32 bh, 32 ci), ci = 31-by (longest-first),
// double-buffered K/V, 41KB LDS -> 3 blocks/CU, lane-local softmax.
// (R11/R13/R15/R17 verified-best structure.)
// ---------------------------------------------------------------------------
__global__ __launch_bounds__(256) void attn(const short* __restrict__ Q,
                                            const short* __restrict__ K,
                                            const short* __restrict__ Vt,
                                            short* __restrict__ O) {
    const int tid  = threadIdx.x;
    const int lane = tid & 63;
    const int w    = tid >> 6;
    const int g = lane >> 4, c16 = lane & 15;
    const int bh = blockIdx.x;                    // 0..31
    const int ci = 31 - blockIdx.y;               // longest-first
    const int ntiles = ci + 1;
    const int wq0 = ci * 64 + w * 16;
    const size_t base = (size_t)bh * S_LEN * DH;
    const short* Kb = K + base;
    const short* Vb = Vt + (size_t)bh * DH * S_LEN;
    const int b = bh >> 4, h = bh & 15;

    __shared__ __align__(16) short KL[2][4096];   // [64 kv][64 d] swizzled chunks
    __shared__ __align__(16) short VL[2][4096];   // [64 d][64 kv] swizzled chunks
    __shared__ __align__(16) short P2[4][16][72]; // per-wave P^T[q][kv]

    const int kr = tid >> 3;                      // 0..31
    const int kc = (tid & 7) ^ (kr & 7);
    const short* kg0 = Kb + (size_t)kr * DH + (kc << 3);
    const short* kg1 = Kb + (size_t)(32 + kr) * DH + (kc << 3);
    const short* vg0 = Vb + (size_t)kr * S_LEN + (kc << 3);
    const short* vg1 = Vb + (size_t)(32 + kr) * S_LEN + (kc << 3);
    const int lw = w * 512;                       // wave-uniform LDS base (shorts)
    const int kx = c16 & 7;

    gload_lds16(kg0, &KL[0][lw]);
    gload_lds16(kg1, &KL[0][2048 + lw]);
    gload_lds16(vg0, &VL[0][lw]);
    gload_lds16(vg1, &VL[0][2048 + lw]);
    s16x8 bq0 = *(const s16x8*)(Q + base + (size_t)(wq0 + c16) * DH + g * 8);
    s16x8 bq1 = *(const s16x8*)(Q + base + (size_t)(wq0 + c16) * DH + 32 + g * 8);
    VM_WAIT(0);
    barrier_sync();

    f32x4 o[4] = {};
    float lsum = 0.f;

    for (int tt = 0; tt < ntiles; ++tt) {
        const int cur = tt & 1;
        const bool more = (tt + 1 < ntiles);
        if (more) {
            const size_t ko = (size_t)(tt + 1) * 64;
            gload_lds16(kg0 + ko * DH, &KL[cur ^ 1][lw]);
            gload_lds16(kg1 + ko * DH, &KL[cur ^ 1][2048 + lw]);
            gload_lds16(vg0 + ko,      &VL[cur ^ 1][lw]);
            gload_lds16(vg1 + ko,      &VL[cur ^ 1][2048 + lw]);
        }

        // QK^T swapped: A=K rows (kv), B=Q -> s[cg] = S^T[kv][q=c16]
        f32x4 s[4];
        __builtin_amdgcn_s_setprio(1);
        #pragma unroll
        for (int cg = 0; cg < 4; ++cg) {
            const int krow = (cg * 16 + c16) * 64;
            s16x8 kf0 = *(const s16x8*)&KL[cur][krow + ((g ^ kx) << 3)];
            s16x8 kf1 = *(const s16x8*)&KL[cur][krow + (((4 + g) ^ kx) << 3)];
            f32x4 zz = {};
            zz = MFMA_BF16(kf0, bq0, zz);
            s[cg] = MFMA_BF16(kf1, bq1, zz);
        }
        __builtin_amdgcn_s_setprio(0);

        s16x8 vf[4][2];
        #pragma unroll
        for (int nt = 0; nt < 4; ++nt) {
            const int vr = (nt * 16 + c16) * 64;
            vf[nt][0] = *(const s16x8*)&VL[cur][vr + ((g ^ kx) << 3)];
            vf[nt][1] = *(const s16x8*)&VL[cur][vr + (((4 + g) ^ kx) << 3)];
        }

        const bool diag = (tt == ci);
        const int qrel = w * 16 + c16;
        #pragma unroll
        for (int cg = 0; cg < 4; ++cg) {
            float e[4];
            #pragma unroll
            for (int r = 0; r < 4; ++r) {
                e[r] = exp2f(s[cg][r]);
                if (diag && (cg * 16 + g * 4 + r > qrel)) e[r] = 0.f;
            }
            lsum += (e[0] + e[1]) + (e[2] + e[3]);
            uint2 pk;
            pk.x = cvtpk_bf16(e[0], e[1]);
            pk.y = cvtpk_bf16(e[2], e[3]);
            *(uint2*)&P2[w][c16][cg * 16 + g * 4] = pk;   // ds_write_b64
        }
        asm volatile("s_waitcnt lgkmcnt(0)" ::: "memory");
        s16x8 ap0 = *(const s16x8*)&P2[w][c16][g * 8];    // ds_read_b128
        s16x8 ap1 = *(const s16x8*)&P2[w][c16][32 + g * 8];

        __builtin_amdgcn_s_setprio(1);
        #pragma unroll
        for (int nt = 0; nt < 4; ++nt) {
            o[nt] = MFMA_BF16(ap0, vf[nt][0], o[nt]);
            o[nt] = MFMA_BF16(ap1, vf[nt][1], o[nt]);
        }
        __builtin_amdgcn_s_setprio(0);

        if (more) { VM_WAIT(0); }                 // next tile landed
        barrier_sync();
    }

    float lt = lsum;
    lt += __shfl_xor(lt, 16, 64);
    lt += __shfl_xor(lt, 32, 64);
    #pragma unroll
    for (int r = 0; r < 4; ++r) {
        const float linv = 1.0f / __shfl(lt, g * 4 + r, 64);
        #pragma unroll
        for (int nt = 0; nt < 4; ++nt) {
            O[((size_t)(b * S_LEN + wq0 + g * 4 + r)) * DMODEL
              + h * DH + nt * 16 + c16] = f2bf(o[nt][r] * linv);
        }
    }
}

// ---------------------------------------------------------------------------
// Output projection: C = Ob(bf16) @ wo, fp32 out. 128x64 tiles, grid (16,32)
// = 512 blocks = 2/CU. XCD remap.
// ---------------------------------------------------------------------------
__global__ __launch_bounds__(256) void gemm_o(const short* __restrict__ Ob,
                                              const short* __restrict__ WoT,
                                              float* __restrict__ C) {
    __shared__ __align__(16) short SMl[18432];    // 36KB

    const int dd = blockIdx.x + 16 * blockIdx.y;  // 0..511, xcd = dd%8
    const int ti = (dd & 7) * 64 + (dd >> 3);     // bijective (512 = 8*64)
    const int tx = ti & 15, ty = ti >> 4;         // ty in [4*xcd, +4)
    const int m0 = ty * 128, n0 = tx * 64;

    f32x4 acc[4][2] = {};
    gemm_tile64(Ob, WoT, m0, n0, SMl, acc);

    const int tid  = threadIdx.x;
    const int lane = tid & 63;
    const int wv   = tid >> 6;
    const int wm   = (wv >> 1) * 64, wn = (wv & 1) * 32;
    const int g = lane >> 4, c16 = lane & 15;

    #pragma unroll
    for (int i = 0; i < 4; ++i)
        #pragma unroll
        for (int j = 0; j < 2; ++j) {
            const int n = n0 + wn + j * 16 + c16;
            #pragma unroll
            for (int r = 0; r < 4; ++r) {
                const int m = m0 + wm + i * 16 + g * 4 + r;
                C[(size_t)m * DMODEL + n] = acc[i][j][r];
            }
        }
}

// ---------------------------------------------------------------------------
extern "C" void kernel_launch(void* const* d_in, const int* in_sizes, int n_in,
                              void* d_out, int out_size, void* d_ws, size_t ws_size,
                              hipStream_t stream) {
    const float* x  = (const float*)d_in[0];
    const float* wq = (const float*)d_in[1];
    const float* wk = (const float*)d_in[2];
    const float* wv = (const float*)d_in[3];
    const float* wo = (const float*)d_in[4];
    float* out = (float*)d_out;

    char* ws = (char*)d_ws;
    short* wtb  = (short*)ws;                              // [4][1024][1024] bf16 (q,k,v,o)
    short* xb   = (short*)(ws + (8ull  << 20));            // [4096][1024] bf16
    float* cosT = (float*)(ws + (16ull << 20));            // [2048][32]
    float* sinT = (float*)(ws + (16ull << 20) + (256ull << 10));
    short* Qb   = (short*)(ws + (17ull << 20));            // [B*H][S][64] bf16 (pre-scaled)
    short* Kb   = (short*)(ws + (25ull << 20));            // [B*H][S][64] bf16
    short* Vtb  = (short*)(ws + (33ull << 20));            // [B*H][64][S] bf16 (transposed)
    short* Ob   = (short*)(ws + (41ull << 20));            // [4096][1024] bf16

    prep_all<<<dim3(16, 16, 8), 256, 0, stream>>>(wq, wk, wv, wo, x,
                                                  wtb, xb, cosT, sinT);

    gemm_qkv<<<dim3(24, 32), 256, 0, stream>>>(xb, wtb, Qb, Kb, Vtb, cosT, sinT);
    attn    <<<dim3(32, 32), 256, 0, stream>>>(Qb, Kb, Vtb, Ob);
    gemm_o  <<<dim3(16, 32), 256, 0, stream>>>(Ob, wtb + 3ull * DMODEL * DMODEL, out);
}